// Round 8
// baseline (13.177 us; speedup 1.0000x reference)
//
#include <hip/hip_runtime.h>

#define NF      2
#define NLOC    3072
#define NALL    4096
#define NNEI    128
#define NTYPES  4
#define NSPLINE 1024

// Opaque VGPR barrier: value becomes unknowable to the optimizer, so no
// contraction (mul+add->fma), reassociation, or approximation can cross it.
__device__ __forceinline__ float opaque(float x) {
    asm volatile("" : "+v"(x));
    return x;
}

__global__ __launch_bounds__(256) void pairtab_kernel(
    const float* __restrict__ coord,     // NF*NALL*3
    const int*   __restrict__ atype,     // NF*NALL
    const int*   __restrict__ nlist,     // NF*NLOC*NNEI
    const float* __restrict__ tab_info,  // 3
    const float* __restrict__ tab_data,  // NTYPES*NTYPES*NSPLINE*4
    float*       __restrict__ out)       // NF*NLOC
{
    const int wave = threadIdx.x >> 6;
    const int lane = threadIdx.x & 63;
    const int row  = blockIdx.x * 4 + wave;
    if (row >= NF * NLOC) return;

    const int f = (row >= NLOC) ? 1 : 0;
    const int i = row - f * NLOC;

    const float rmin = tab_info[0];
    const float hh   = tab_info[1];
    // DeePMD numpy: hi = 1.0 / hh  (CR f32 reciprocal; f64-div+round is
    // double-rounding-safe == numpy's correctly-rounded f32 divide)
    const float hi = opaque((float)(1.0 / (double)hh));
    // beyond2 = rmin + NSPLINE*hh in f32 (= 6.144 > RCUT, effectively unused)
    const float cut2 = opaque(opaque(1024.0f * hh) + rmin);

    const float* ci = coord + (size_t)(f * NALL + i) * 3;
    const float xi = ci[0], yi = ci[1], zi = ci[2];
    const int itype = atype[f * NALL + i];

    const size_t base_nl = (size_t)(f * NLOC + i) * NNEI;

    double acc = 0.0;

    #pragma unroll
    for (int t = 0; t < 2; ++t) {
        const int jj = lane + t * 64;
        const int nj = nlist[base_nl + jj];
        const int mj = (nj < 0) ? 0 : nj;

        const float* cj = coord + (size_t)(f * NALL + mj) * 3;

        // ---- strict f32, numpy association, every op barriered ----
        const float dx = opaque(xi - cj[0]);
        const float dy = opaque(yi - cj[1]);
        const float dz = opaque(zi - cj[2]);
        const float x2 = opaque(dx * dx);
        const float y2 = opaque(dy * dy);
        const float z2 = opaque(dz * dz);
        float ss = opaque(opaque(x2 + y2) + z2);
        ss = fmaxf(ss, 1e-30f);   // affects only masked self-pairs (zeroed)

        // CR f32 sqrt, flag-immune: f64 sqrt then round (double-rounding safe)
        const float rr = (float)sqrt((double)ss);

        // DeePMD numpy: uu = (rr - rmin) * hi   (f32 sub, f32 mul; NO divide)
        const float num = opaque(rr - rmin);
        float uu = opaque(num * hi);
        if (nj == -1) uu = (float)(NSPLINE + 1);

        const int idx = (int)uu;                  // trunc, uu >= 0
        const float fu = opaque(uu - (float)idx); // exact in f32
        int cidx = idx;
        if (cidx < 0) cidx = 0;
        if (cidx > NSPLINE - 1) cidx = NSPLINE - 1;

        const int jtype = atype[f * NALL + mj];
        const float4 c4 = *(const float4*)(tab_data +
            ((size_t)((itype * NTYPES + jtype) * NSPLINE + cidx)) * 4);

        float a3 = c4.x, a2 = c4.y, a1 = c4.z, a0 = c4.w;
        if (idx > NSPLINE) { a3 = 0.f; a2 = 0.f; a1 = 0.f; a0 = 0.f; }

        // DeePMD _calculate_ener, f32 unfused Horner:
        // etmp = (a3*u + a2)*u + a1 ; e = etmp*u + a0
        float e = opaque(opaque(opaque(opaque(opaque(a3 * fu) + a2) * fu)
                                + a1) * fu) + a0;

        if (rr >= 6.0f || rr >= cut2 || nj == -1) e = 0.0f;
        acc += (double)e;
    }

    // wave-64 butterfly reduction (f64; order-diff vs numpy invisible)
    #pragma unroll
    for (int off = 32; off; off >>= 1)
        acc += __shfl_xor(acc, off);

    if (lane == 0) out[row] = (float)(0.5 * acc);
}

extern "C" void kernel_launch(void* const* d_in, const int* in_sizes, int n_in,
                              void* d_out, int out_size, void* d_ws, size_t ws_size,
                              hipStream_t stream) {
    const float* coord    = (const float*)d_in[0];
    const int*   atype    = (const int*)  d_in[1];
    const int*   nlist    = (const int*)  d_in[2];
    const float* tab_info = (const float*)d_in[3];
    const float* tab_data = (const float*)d_in[4];
    float* out = (float*)d_out;

    const int rows = NF * NLOC;                 // 6144
    const int blocks = rows / 4;                // 4 rows (waves) per 256-thread block
    pairtab_kernel<<<blocks, 256, 0, stream>>>(coord, atype, nlist, tab_info,
                                               tab_data, out);
}

// Round 9
// 13.149 us; speedup vs baseline: 1.0021x; 1.0021x over previous
//
#include <hip/hip_runtime.h>

#define NF      2
#define NLOC    3072
#define NALL    4096
#define NNEI    128
#define NTYPES  4
#define NSPLINE 1024

// Opaque VGPR barrier: value becomes unknowable to the optimizer, so no
// contraction (mul+add->fma), reassociation, or approximation can cross it.
__device__ __forceinline__ float opaque(float x) {
    asm volatile("" : "+v"(x));
    return x;
}

// One thread per (row, neighbor). 256-thread block = 2 rows x 128 neighbors.
__global__ __launch_bounds__(256) void pairtab_kernel(
    const float* __restrict__ coord,     // NF*NALL*3
    const int*   __restrict__ atype,     // NF*NALL
    const int*   __restrict__ nlist,     // NF*NLOC*NNEI
    const float* __restrict__ tab_info,  // 3
    const float* __restrict__ tab_data,  // NTYPES*NTYPES*NSPLINE*4
    float*       __restrict__ out)       // NF*NLOC
{
    const int tid   = threadIdx.x;
    const int r     = tid >> 7;          // row within block (0..1)
    const int jj    = tid & 127;         // neighbor index
    const int row   = blockIdx.x * 2 + r;

    const int f = (row >= NLOC) ? 1 : 0;
    const int i = row - f * NLOC;

    const float rmin = tab_info[0];
    const float hh   = tab_info[1];
    // DeePMD numpy: hi = 1.0 / hh (CR f32 via f64-div+round, double-rounding safe)
    const float hi   = opaque((float)(1.0 / (double)hh));
    const float cut2 = opaque(opaque(1024.0f * hh) + rmin);

    const float* ci = coord + (size_t)(f * NALL + i) * 3;
    const float xi = ci[0], yi = ci[1], zi = ci[2];
    const int itype = atype[f * NALL + i];

    const int nj = nlist[(size_t)(f * NLOC + i) * NNEI + jj];
    const int mj = (nj < 0) ? 0 : nj;

    const float* cj = coord + (size_t)(f * NALL + mj) * 3;

    // ---- strict f32, numpy association, every op barriered (no FMA) ----
    const float dx = opaque(xi - cj[0]);
    const float dy = opaque(yi - cj[1]);
    const float dz = opaque(zi - cj[2]);
    const float x2 = opaque(dx * dx);
    const float y2 = opaque(dy * dy);
    const float z2 = opaque(dz * dz);
    float ss = opaque(opaque(x2 + y2) + z2);
    ss = fmaxf(ss, 1e-30f);

    // CR f32 sqrt, flag-immune: f64 sqrt then round (double-rounding safe)
    const float rr = (float)sqrt((double)ss);

    // uu = (rr - rmin) * hi   (f32 sub, f32 mul — matches DeePMD numpy)
    const float num = opaque(rr - rmin);
    float uu = opaque(num * hi);
    if (nj == -1) uu = (float)(NSPLINE + 1);

    const int idx = (int)uu;                  // trunc, uu >= 0
    const float fu = opaque(uu - (float)idx);
    int cidx = idx;
    if (cidx < 0) cidx = 0;
    if (cidx > NSPLINE - 1) cidx = NSPLINE - 1;

    const int jtype = atype[f * NALL + mj];
    const float4 c4 = *(const float4*)(tab_data +
        ((size_t)((itype * NTYPES + jtype) * NSPLINE + cidx)) * 4);

    float a3 = c4.x, a2 = c4.y, a1 = c4.z, a0 = c4.w;
    if (idx > NSPLINE) { a3 = 0.f; a2 = 0.f; a1 = 0.f; a0 = 0.f; }

    // f32 unfused Horner (DeePMD _calculate_ener)
    float e = opaque(opaque(opaque(opaque(opaque(a3 * fu) + a2) * fu)
                            + a1) * fu) + a0;

    if (rr >= 6.0f || rr >= cut2 || nj == -1) e = 0.0f;

    // ---- reduction: wave shfl + LDS combine (2 waves per row) ----
    double acc = (double)e;
    #pragma unroll
    for (int off = 32; off; off >>= 1)
        acc += __shfl_xor(acc, off);

    __shared__ double part[4];
    if ((tid & 63) == 0) part[tid >> 6] = acc;
    __syncthreads();
    if (jj == 0)
        out[row] = (float)(0.5 * (part[r * 2] + part[r * 2 + 1]));
}

extern "C" void kernel_launch(void* const* d_in, const int* in_sizes, int n_in,
                              void* d_out, int out_size, void* d_ws, size_t ws_size,
                              hipStream_t stream) {
    const float* coord    = (const float*)d_in[0];
    const int*   atype    = (const int*)  d_in[1];
    const int*   nlist    = (const int*)  d_in[2];
    const float* tab_info = (const float*)d_in[3];
    const float* tab_data = (const float*)d_in[4];
    float* out = (float*)d_out;

    const int blocks = (NF * NLOC) / 2;          // 3072 blocks, 2 rows each
    pairtab_kernel<<<blocks, 256, 0, stream>>>(coord, atype, nlist, tab_info,
                                               tab_data, out);
}